// Round 1
// baseline (81.302 us; speedup 1.0000x reference)
//
#include <hip/hip_runtime.h>
#include <float.h>

#define FH 64
#define FW 64
#define FC 256
#define NB 4
#define NR 128
#define NREG 32
#define POOLH 3
#define POOLW 3
#define IOU_THR 0.4f
#define NCELL (POOLH * POOLW)

#define POOLED_ELEMS (NB * NREG * NCELL * FC)

// Per-(batch,region,cell) pooling metadata written by nms_kernel, read by
// pool_kernel. Static device memory: no hipMalloc, graph-capture safe, and
// kernel-boundary ordering on the stream guarantees visibility.
__device__ int4 g_meta[NB * NREG * NCELL];

// Python floor-division semantics for /2 on possibly-negative ints:
// arithmetic shift right == floor division by 2 on two's complement.
__device__ inline void fix_axis(int mn, int mx, int ps, int fs, int& omin, int& omax) {
    int pad = ps - (mx - mn);
    bool fix_min = mn < (pad >> 1);
    bool fix_max = (fs - mx) < ((1 + pad) >> 1);
    bool sym = (pad > 0) && !(fix_min || fix_max);
    omin = sym ? (mn - (pad >> 1)) : mn;
    omax = sym ? (mx + ((1 + pad) >> 1)) : mx;
    if ((pad > 0) && fix_min) { omin = 0; omax = ps; }
    if ((pad > 0) && fix_max) { omin = fs - ps; omax = fs; }
}

__device__ inline float4 max4(float4 a, float4 b) {
    float4 o;
    o.x = fmaxf(a.x, b.x); o.y = fmaxf(a.y, b.y);
    o.z = fmaxf(a.z, b.z); o.w = fmaxf(a.w, b.w);
    return o;
}

// Broadcast lane `lane`'s 64-bit value to all lanes of the wave (lane uniform).
__device__ inline unsigned long long readlane64(unsigned long long v, int lane) {
    unsigned lo = (unsigned)__builtin_amdgcn_readlane((int)(unsigned)v, lane);
    unsigned hi = (unsigned)__builtin_amdgcn_readlane((int)(unsigned)(v >> 32), lane);
    return ((unsigned long long)hi << 32) | lo;
}

// ---------------------------------------------------------------------------
// Kernel A: one block per batch. Bitmask NMS (row-build across 256 threads),
// serial kept-bit resolve on wave 0 recording ALL 32 kept indices, clip,
// write roi_clipped, and precompute per-cell pooling metadata.
// ---------------------------------------------------------------------------
__global__ __launch_bounds__(256) void nms_kernel(
    const float* __restrict__ roi,   // (B, R, 4)
    float* __restrict__ out)         // pooled ++ roi_clipped
{
    const int b = blockIdx.x;
    const int tid = threadIdx.x;

    __shared__ float sx1[NR], sy1[NR], sx2[NR], sy2[NR], sarea[NR];
    __shared__ unsigned long long smask[NR][2];
    __shared__ int skeep[NREG];
    __shared__ int sclip[NREG][4];

    if (tid < NR) {
        const float4 bx = *(const float4*)(roi + ((size_t)b * NR + tid) * 4);
        sx1[tid] = bx.x; sy1[tid] = bx.y;
        sx2[tid] = bx.x + bx.z; sy2[tid] = bx.y + bx.w;
        sarea[tid] = bx.z * bx.w;
    }
    if (tid < NREG) skeep[tid] = NR - 1;   // pad: missing kept -> box 127
    __syncthreads();

    // Row-build: p = tid&127 owns row p; half = tid>>7 covers 64 j's.
    // Division-free IoU: inter/(A+B-inter) > t <=> inter > t*(A+B-inter).
    {
        const int p = tid & 127;
        const int half = tid >> 7;
        const int j0 = half << 6;
        const float px1 = sx1[p], py1 = sy1[p], px2 = sx2[p], py2 = sy2[p], pa = sarea[p];
        unsigned long long m = 0ull;
        #pragma unroll 8
        for (int t = 0; t < 64; ++t) {
            const int jj = j0 + t;
            float iw = fmaxf(fminf(px2, sx2[jj]) - fmaxf(px1, sx1[jj]), 0.0f);
            float ih = fmaxf(fminf(py2, sy2[jj]) - fmaxf(py1, sy1[jj]), 0.0f);
            float inter = iw * ih;
            bool sup = (jj > p) && (inter > IOU_THR * (pa + sarea[jj] - inter));
            m |= ((unsigned long long)sup) << t;
        }
        smask[p][half] = m;
    }
    __syncthreads();

    // Resolve on wave 0: enumerate final-kept boxes in ascending order,
    // recording each into skeep. Rows live in wave-0 registers (readlane).
    if (tid < 64) {
        const int lane = tid;
        const unsigned long long aLo = smask[tid][0];       // row tid, bits [0,64)
        const unsigned long long aHi = smask[tid][1];       // row tid, bits [64,128)
        const unsigned long long bHi = smask[tid + 64][1];  // row tid+64 (low half 0)

        unsigned long long k1 = ~0ull;   // half-1 survivors under half-0 kept rows
        int cnt = 0;

        unsigned long long cur = ~0ull;  // half-0 candidates
        while (cur && cnt < NREG) {
            int p = __ffsll((unsigned long long)cur) - 1;
            if (lane == 0) skeep[cnt] = p;
            ++cnt;
            int ps = __builtin_amdgcn_readfirstlane(p);
            unsigned long long m0 = readlane64(aLo, ps);
            unsigned long long m1 = readlane64(aHi, ps);
            cur = (cur & (cur - 1)) & ~m0;   // drop p + its suppressions
            k1 &= ~m1;
        }
        cur = k1;
        while (cur && cnt < NREG) {
            int p = __ffsll((unsigned long long)cur) - 1;
            if (lane == 0) skeep[cnt] = 64 + p;
            ++cnt;
            int ps = __builtin_amdgcn_readfirstlane(p);
            unsigned long long m1 = readlane64(bHi, ps);
            cur = (cur & (cur - 1)) & ~m1;
        }
    }
    __syncthreads();

    // Clip all 32 selected boxes; write roi_clipped.
    if (tid < NREG) {
        const int idx = skeep[tid];
        float x1 = sx1[idx], y1 = sy1[idx], x2f = sx2[idx], y2f = sy2[idx];
        int x_min = (int)fmaxf(0.0f, x1);
        int y_min = (int)fmaxf(0.0f, y1);
        int x_max = (int)fminf((float)FW, x2f);
        int y_max = (int)fminf((float)FH, y2f);
        int xmn, xmx, ymn, ymx;
        fix_axis(x_min, x_max, POOLW, FW, xmn, xmx);
        fix_axis(y_min, y_max, POOLH, FH, ymn, ymx);
        sclip[tid][0] = xmn; sclip[tid][1] = ymn;
        sclip[tid][2] = xmx - xmn; sclip[tid][3] = ymx - ymn;
        float* orc = out + POOLED_ELEMS + ((size_t)(b * NREG + tid)) * 4;
        orc[0] = (float)xmn;
        orc[1] = (float)ymn;
        orc[2] = (float)(xmx - xmn);
        orc[3] = (float)(ymx - ymn);
    }
    __syncthreads();

    // Per-(region,cell) pooling metadata: {base0, n, magicM, ncols}.
    for (int e = tid; e < NREG * NCELL; e += 256) {
        const int rr = e / NCELL;
        const int cell = e - rr * NCELL;
        const int ci = cell / POOLW, cj = cell - ci * POOLW;
        const int x = sclip[rr][0], y = sclip[rr][1];
        const int w = sclip[rr][2], h = sclip[rr][3];
        const int hh = h / POOLH;
        const int ww = w / POOLW;
        const int r0 = y + ci * hh;
        const int r1 = (ci < POOLH - 1) ? (y + (ci + 1) * hh) : (y + h);
        const int c0 = x + cj * ww;
        const int c1 = (cj < POOLW - 1) ? (x + (cj + 1) * ww) : (x + w);
        const int ncols = c1 - c0;                 // 1..12
        const int n = (r1 - r0) * ncols;           // 1..144
        const int M = 65536 / ncols + 1;           // magic for /ncols, k<=159 exact
        const int base0 = (r0 * FW + c0) * FC;
        g_meta[(size_t)(b * NREG + rr) * NCELL + cell] = make_int4(base0, n, M, ncols);
    }
}

// ---------------------------------------------------------------------------
// Kernel B: one block per (region, pool-cell). Pure pooling: one uniform
// metadata load, in-register pixel-offset computation (no spix LDS, no
// pre-pool barriers), float4 gathers with 4 loads in flight per group.
// ---------------------------------------------------------------------------
__global__ __launch_bounds__(256) void pool_kernel(
    const float* __restrict__ features,  // (B, H, W, C)
    float* __restrict__ out)             // pooled (B,32,3,3,C)
{
    // XCD batch-affinity swizzle: consecutive hw block IDs round-robin the 8
    // XCDs (id & 7). Put batch b's 288 blocks on XCD pair {2b, 2b+1} so its
    // 4 MB feature slab stays resident in 8 MB of paired L2.
    const int hwid = blockIdx.x;
    const int b = (hwid >> 1) & 3;
    const int j = (hwid >> 3) * 2 + (hwid & 1);   // 0..287 within batch
    const int r = j / NCELL;                      // region 0..31
    const int cell = j - r * NCELL;               // 0..8
    const int reg = b * NREG + r;
    const int tid = threadIdx.x;
    const int group = tid >> 6;                   // 0..3
    const int lane = tid & 63;

    __shared__ float4 sred[4][64];

    // Wave-uniform address -> compiler emits scalar load.
    const int4 meta = g_meta[(size_t)reg * NCELL + cell];
    const int base0 = meta.x;
    const int n     = meta.y;
    const int M     = meta.z;
    const int ncols = meta.w;

    const float* fbase = features + (size_t)b * FH * FW * FC;
    const float4 negv = {-FLT_MAX, -FLT_MAX, -FLT_MAX, -FLT_MAX};
    float4 m0 = negv, m1 = negv, m2 = negv, m3 = negv;

    // offset(k) = ((r0+q)*FW + (c0+cc)) * FC = base0 + q*16384 + cc*256
    auto off = [&](int k) -> int {
        int q = (k * M) >> 16;        // k / ncols (exact for k<=159, ncols<=12)
        int cc = k - q * ncols;
        return base0 + (q << 14) + (cc << 8);
    };

    int k = group;
    for (; k + 12 < n; k += 16) {
        int o0 = off(k), o1 = off(k + 4), o2 = off(k + 8), o3 = off(k + 12);
        float4 v0 = ((const float4*)(fbase + o0))[lane];
        float4 v1 = ((const float4*)(fbase + o1))[lane];
        float4 v2 = ((const float4*)(fbase + o2))[lane];
        float4 v3 = ((const float4*)(fbase + o3))[lane];
        m0 = max4(m0, v0); m1 = max4(m1, v1);
        m2 = max4(m2, v2); m3 = max4(m3, v3);
    }
    for (; k < n; k += 4) {
        float4 v = ((const float4*)(fbase + off(k)))[lane];
        m0 = max4(m0, v);
    }
    sred[group][lane] = max4(max4(m0, m1), max4(m2, m3));
    __syncthreads();

    // Final reduce over the 4 groups; coalesced float4 store.
    if (tid < 64) {
        float4 a = max4(max4(sred[0][tid], sred[1][tid]),
                        max4(sred[2][tid], sred[3][tid]));
        float4* ob = (float4*)(out + ((size_t)reg * NCELL + cell) * FC);
        ob[tid] = a;
    }
}

extern "C" void kernel_launch(void* const* d_in, const int* in_sizes, int n_in,
                              void* d_out, int out_size, void* d_ws, size_t ws_size,
                              hipStream_t stream) {
    const float* features = (const float*)d_in[0];  // (4, 64, 64, 256) f32
    const float* roi = (const float*)d_in[1];       // (4, 128, 4) f32
    float* out = (float*)d_out;                     // 294912 + 512 f32 elems
    (void)in_sizes; (void)n_in; (void)out_size; (void)d_ws; (void)ws_size;

    nms_kernel<<<NB, 256, 0, stream>>>(roi, out);
    pool_kernel<<<NB * NREG * NCELL, 256, 0, stream>>>(features, out);
}